// Round 18
// baseline (7929.253 us; speedup 1.0000x reference)
//
#include <hip/hip_runtime.h>
#include <hip/hip_bf16.h>
#include <stdint.h>

#define BS 512
#define D 1024
#define H 4096
#define T_STEPS 64
#define N_INNER 4
#define SK 8

typedef __attribute__((ext_vector_type(8))) _Float16 f16x8;
typedef __attribute__((ext_vector_type(4))) float f32x4;
typedef __attribute__((ext_vector_type(4))) unsigned short u16x4;
typedef unsigned short u16;

__device__ __forceinline__ u16 f2h_bits(float f) {
    _Float16 h = (_Float16)f;
    return __builtin_bit_cast(u16, h);
}
__device__ __forceinline__ float h2f(u16 b) {
    return (float)__builtin_bit_cast(_Float16, b);
}
__device__ __forceinline__ float fast_tanh(float x) {
    float e = __expf(2.0f * x);
    return 1.0f - 2.0f / (e + 1.0f);
}

// ---------------- prep kernels ----------------

// src [rows][cols] f32 -> dst [cols][rows] single fp16 (for W1)
__global__ __launch_bounds__(256) void transpose_h(
    const float* __restrict__ src, u16* __restrict__ dst, int rows, int cols) {
    __shared__ float tile[32][33];
    const int tx = threadIdx.x & 31;
    const int ty = threadIdx.x >> 5;
    const int c0 = blockIdx.x * 32, r0 = blockIdx.y * 32;
    #pragma unroll
    for (int i = ty; i < 32; i += 8)
        tile[i][tx] = src[(size_t)(r0 + i) * cols + c0 + tx];
    __syncthreads();
    #pragma unroll
    for (int i = ty; i < 32; i += 8)
        dst[(size_t)(c0 + i) * rows + r0 + tx] = f2h_bits(tile[tx][i]);
}

// src [rows][cols] f32 -> dst_hi/dst_lo [cols][rows] fp16 hi+lo (for W2)
__global__ __launch_bounds__(256) void transpose_split(
    const float* __restrict__ src, u16* __restrict__ dst_hi,
    u16* __restrict__ dst_lo, int rows, int cols) {
    __shared__ float tile[32][33];
    const int tx = threadIdx.x & 31;
    const int ty = threadIdx.x >> 5;
    const int c0 = blockIdx.x * 32, r0 = blockIdx.y * 32;
    #pragma unroll
    for (int i = ty; i < 32; i += 8)
        tile[i][tx] = src[(size_t)(r0 + i) * cols + c0 + tx];
    __syncthreads();
    #pragma unroll
    for (int i = ty; i < 32; i += 8) {
        const float v = tile[tx][i];
        const u16 hi = f2h_bits(v);
        const u16 lo = f2h_bits(v - h2f(hi));
        const size_t idx = (size_t)(c0 + i) * rows + r0 + tx;
        dst_hi[idx] = hi;
        dst_lo[idx] = lo;
    }
}

__global__ __launch_bounds__(256) void init_z(
    const float* __restrict__ z0, float* __restrict__ z_cur,
    u16* __restrict__ z_h, float* __restrict__ out) {
    const int i = blockIdx.x * 256 + threadIdx.x;
    const float v = z0[i];
    z_cur[i] = v;
    z_h[i] = f2h_bits(v);
    out[i] = v;
}

// ---------------- staging helpers (rule #21 swizzle, r4/r10-proven) ----------
// NR rows x 64 cols fp16 (128 B rows): linear LDS dest, inverse-swizzled src.
template<int NISS>
__device__ __forceinline__ void stage_rows(
    const u16* __restrict__ src, u16* lds, int row0, int ldK, int k0, int tid) {
    #pragma unroll
    for (int i = 0; i < NISS; ++i) {
        const int L = (i * 256 + tid) * 16;        // byte offset in tile
        const int r = L >> 7;
        const int cb = (L & 127) ^ ((r & 7) << 4);
        const size_t goff = (size_t)(row0 + r) * ldK + k0 + (cb >> 1);
        const int ldsoff = (i * 256 + (tid & ~63)) * 8;  // elems, wave-uniform
        __builtin_amdgcn_global_load_lds(
            (const __attribute__((address_space(1))) void*)(src + goff),
            (__attribute__((address_space(3))) void*)(lds + ldsoff), 16, 0, 0);
    }
}

// ---------------- GEMM1: 128x64 tile, single-fp16 W1 -------------------------
// hid = tanh(z @ W1 + b1). BM=128, BN=64, BK=64, 16 kt. Grid 256 (4 tm x
// 64 tn, XCD-grouped). 4 waves (2x2), each 64x32 (acc 4x2). Depth-2
// double-buffer (48 KB LDS), counted vmcnt(6) (A 4 + B 2 loads/wave/stage),
// 2 barriers/iter — structure copied verbatim from r17's passing gemm2.
__global__ __launch_bounds__(256, 2) void gemm1_step(
    const u16* __restrict__ A_h, const u16* __restrict__ B_w,
    const float* __restrict__ bias, u16* __restrict__ hid_out) {
    __shared__ __align__(16) u16 lA[2][8192];     // 128x64
    __shared__ __align__(16) u16 lB[2][4096];     // 64x64

    const int tid = threadIdx.x;
    const int bid = blockIdx.x;
    const int xcd = bid & 7, loc = bid >> 3;      // loc 0..31
    const int tn = xcd * 8 + (loc & 7);           // 0..63
    const int tm = loc >> 3;                      // 0..3
    const int m0 = tm * 128, n0 = tn * 64;

    const int wave = tid >> 6;
    const int lane = tid & 63;
    const int wr = wave >> 1, wc = wave & 1;      // wave owns 64x32
    const int l15 = lane & 15;
    const int lgrp = lane >> 4;
    const int lk8 = lgrp * 8;

    f32x4 acc[4][2];
    #pragma unroll
    for (int mi = 0; mi < 4; ++mi)
        #pragma unroll
        for (int ni = 0; ni < 2; ++ni)
            acc[mi][ni] = (f32x4){0.f, 0.f, 0.f, 0.f};

    auto STAGE = [&](int buf, int kt) {
        const int k0 = kt * 64;
        stage_rows<4>(A_h, lA[buf], m0, D, k0, tid);
        stage_rows<2>(B_w, lB[buf], n0, D, k0, tid);   // 6 loads/wave
    };
    auto COMPUTE = [&](int buf) {
        const char* Ah = (const char*)lA[buf];
        const char* Bh = (const char*)lB[buf];
        #pragma unroll
        for (int kk = 0; kk < 64; kk += 32) {
            f16x8 af[4], bf[2];
            #pragma unroll
            for (int mi = 0; mi < 4; ++mi) {
                const int row = wr * 64 + mi * 16 + l15;
                const int cb = ((kk + lk8) * 2) ^ ((row & 7) << 4);
                af[mi] = *(const f16x8*)(Ah + row * 128 + cb);
            }
            #pragma unroll
            for (int ni = 0; ni < 2; ++ni) {
                const int row = wc * 32 + ni * 16 + l15;
                const int cb = ((kk + lk8) * 2) ^ ((row & 7) << 4);
                bf[ni] = *(const f16x8*)(Bh + row * 128 + cb);
            }
            #pragma unroll
            for (int mi = 0; mi < 4; ++mi)
                #pragma unroll
                for (int ni = 0; ni < 2; ++ni)
                    acc[mi][ni] = __builtin_amdgcn_mfma_f32_16x16x32_f16(
                        af[mi], bf[ni], acc[mi][ni], 0, 0, 0);
        }
    };

    STAGE(0, 0);
    STAGE(1, 1);
    int cur = 0;
    for (int kt = 0; kt < 16; ++kt) {
        if (kt < 15) asm volatile("s_waitcnt vmcnt(6)" ::: "memory");
        else         asm volatile("s_waitcnt vmcnt(0)" ::: "memory");
        asm volatile("s_barrier" ::: "memory");
        COMPUTE(cur);
        if (kt < 14) {
            asm volatile("s_barrier" ::: "memory");   // all waves done with cur
            STAGE(cur, kt + 2);
        }
        cur ^= 1;
    }

    const int crow_base = m0 + wr * 64;
    const int ccol_base = n0 + wc * 32;
    #pragma unroll
    for (int mi = 0; mi < 4; ++mi)
        #pragma unroll
        for (int ni = 0; ni < 2; ++ni) {
            const int col = ccol_base + ni * 16 + l15;
            const float b = bias[col];
            #pragma unroll
            for (int r = 0; r < 4; ++r) {
                const int row = crow_base + mi * 16 + lgrp * 4 + r;
                const float v = fast_tanh(acc[mi][ni][r] + b);
                hid_out[(size_t)row * H + col] = f2h_bits(v);
            }
        }
}

// ---------------- GEMM2 (r17-verbatim): 128x64, SK=8, W2 split hi/lo ---------
__global__ __launch_bounds__(256, 2) void gemm2_step(
    const u16* __restrict__ A_h,
    const u16* __restrict__ B_hi, const u16* __restrict__ B_lo,
    float* __restrict__ part) {
    __shared__ __align__(16) u16 lA[2][8192];     // 128x64
    __shared__ __align__(16) u16 lBh[2][4096];    // 64x64
    __shared__ __align__(16) u16 lBl[2][4096];

    const int tid = threadIdx.x;
    const int bid = blockIdx.x;
    const int xcd = bid & 7, loc = bid >> 3;      // loc 0..63
    const int tn = xcd * 2 + (loc & 1);           // 0..15
    const int tm = (loc >> 1) & 3;                // 0..3
    const int sk = loc >> 3;                      // 0..7
    const int m0 = tm * 128, n0 = tn * 64;
    const int k0b = sk * 512;

    const int wave = tid >> 6;
    const int lane = tid & 63;
    const int wr = wave >> 1, wc = wave & 1;      // wave owns 64x32
    const int l15 = lane & 15;
    const int lgrp = lane >> 4;
    const int lk8 = lgrp * 8;

    f32x4 acc[4][2];
    #pragma unroll
    for (int mi = 0; mi < 4; ++mi)
        #pragma unroll
        for (int ni = 0; ni < 2; ++ni)
            acc[mi][ni] = (f32x4){0.f, 0.f, 0.f, 0.f};

    auto STAGE = [&](int buf, int kt) {
        const int k0 = k0b + kt * 64;
        stage_rows<4>(A_h,  lA[buf],  m0, H, k0, tid);
        stage_rows<2>(B_hi, lBh[buf], n0, H, k0, tid);
        stage_rows<2>(B_lo, lBl[buf], n0, H, k0, tid);   // 8 loads/wave
    };
    auto COMPUTE = [&](int buf) {
        const char* Ah = (const char*)lA[buf];
        const char* Bh = (const char*)lBh[buf];
        const char* Bl = (const char*)lBl[buf];
        #pragma unroll
        for (int kk = 0; kk < 64; kk += 32) {
            f16x8 af[4], bfh[2], bfl[2];
            #pragma unroll
            for (int mi = 0; mi < 4; ++mi) {
                const int row = wr * 64 + mi * 16 + l15;
                const int cb = ((kk + lk8) * 2) ^ ((row & 7) << 4);
                af[mi] = *(const f16x8*)(Ah + row * 128 + cb);
            }
            #pragma unroll
            for (int ni = 0; ni < 2; ++ni) {
                const int row = wc * 32 + ni * 16 + l15;
                const int cb = ((kk + lk8) * 2) ^ ((row & 7) << 4);
                bfh[ni] = *(const f16x8*)(Bh + row * 128 + cb);
                bfl[ni] = *(const f16x8*)(Bl + row * 128 + cb);
            }
            #pragma unroll
            for (int mi = 0; mi < 4; ++mi)
                #pragma unroll
                for (int ni = 0; ni < 2; ++ni) {
                    acc[mi][ni] = __builtin_amdgcn_mfma_f32_16x16x32_f16(
                        af[mi], bfh[ni], acc[mi][ni], 0, 0, 0);
                    acc[mi][ni] = __builtin_amdgcn_mfma_f32_16x16x32_f16(
                        af[mi], bfl[ni], acc[mi][ni], 0, 0, 0);
                }
        }
    };

    STAGE(0, 0);
    STAGE(1, 1);
    int cur = 0;
    for (int kt = 0; kt < 8; ++kt) {
        if (kt < 7) asm volatile("s_waitcnt vmcnt(8)" ::: "memory");
        else        asm volatile("s_waitcnt vmcnt(0)" ::: "memory");
        asm volatile("s_barrier" ::: "memory");
        COMPUTE(cur);
        if (kt < 6) {
            asm volatile("s_barrier" ::: "memory");
            STAGE(cur, kt + 2);
        }
        cur ^= 1;
    }

    float* p = part + (size_t)sk * BS * D;
    const int crow_base = m0 + wr * 64;
    const int ccol_base = n0 + wc * 32;
    #pragma unroll
    for (int mi = 0; mi < 4; ++mi)
        #pragma unroll
        for (int ni = 0; ni < 2; ++ni) {
            const int col = ccol_base + ni * 16 + l15;
            #pragma unroll
            for (int r = 0; r < 4; ++r) {
                const int row = crow_base + mi * 16 + lgrp * 4 + r;
                p[(size_t)row * D + col] = acc[mi][ni][r];
            }
        }
}

// ---------------- split-K reduce (SK=8) + Euler update (r17-verbatim) --------
__global__ __launch_bounds__(256) void reduce_update(
    const float* __restrict__ part, const float* __restrict__ b2,
    const float* __restrict__ z_in, float* __restrict__ z_out,
    u16* __restrict__ zh,
    float* __restrict__ traj, const float* __restrict__ tptr, int iv) {
    const int i = (blockIdx.x * 256 + threadIdx.x) * 4;
    const size_t SZ = (size_t)BS * D;
    float4 s = *(const float4*)(part + i);
    #pragma unroll
    for (int k = 1; k < SK; ++k) {
        const float4 pk = *(const float4*)(part + (size_t)k * SZ + i);
        s.x += pk.x; s.y += pk.y; s.z += pk.z; s.w += pk.w;
    }
    const float4 b = *(const float4*)(b2 + (i & (D - 1)));
    const float4 z = *(const float4*)(z_in + i);
    const float h = fabsf(tptr[iv + 1] - tptr[iv]) * (1.0f / N_INNER);
    float4 v;
    v.x = z.x + h * (s.x + b.x);
    v.y = z.y + h * (s.y + b.y);
    v.z = z.z + h * (s.z + b.z);
    v.w = z.w + h * (s.w + b.w);
    *(float4*)(z_out + i) = v;
    u16x4 h4;
    h4.x = f2h_bits(v.x);
    h4.y = f2h_bits(v.y);
    h4.z = f2h_bits(v.z);
    h4.w = f2h_bits(v.w);
    *(u16x4*)(zh + i) = h4;
    if (traj) *(float4*)(traj + i) = v;
}

// ---------------- host ----------------

extern "C" void kernel_launch(void* const* d_in, const int* in_sizes, int n_in,
                              void* d_out, int out_size, void* d_ws, size_t ws_size,
                              hipStream_t stream) {
    const float* z0 = (const float*)d_in[0];
    const float* t  = (const float*)d_in[1];
    const float* W1 = (const float*)d_in[2];
    const float* b1 = (const float*)d_in[3];
    const float* W2 = (const float*)d_in[4];
    const float* b2 = (const float*)d_in[5];
    float* out = (float*)d_out;

    char* ws = (char*)d_ws;
    u16*   W1T    = (u16*)(ws);                        // [H][D] fp16, 8 MB
    u16*   W2T_hi = (u16*)(ws + (8u << 20));           // [D][H] fp16, 8 MB
    u16*   W2T_lo = (u16*)(ws + (16u << 20));
    float* z_cur  = (float*)(ws + (24u << 20));        // [BS][D] f32, 2 MB
    u16*   z_h    = (u16*)(ws + (26u << 20));          // [BS][D] fp16, 1 MB
    u16*   hid_h  = (u16*)(ws + (28u << 20));          // [BS][H] fp16, 4 MB
    float* part   = (float*)(ws + (32u << 20));        // SK x [BS][D] f32, 16 MB

    transpose_h<<<dim3(H / 32, D / 32), 256, 0, stream>>>(W1, W1T, D, H);
    transpose_split<<<dim3(D / 32, H / 32), 256, 0, stream>>>(W2, W2T_hi, W2T_lo, H, D);
    init_z<<<(BS * D) / 256, 256, 0, stream>>>(z0, z_cur, z_h, out);

    for (int iv = 0; iv < T_STEPS - 1; ++iv) {
        for (int s = 0; s < N_INNER; ++s) {
            gemm1_step<<<256, 256, 0, stream>>>(z_h, W1T, b1, hid_h);
            gemm2_step<<<512, 256, 0, stream>>>(hid_h, W2T_hi, W2T_lo, part);
            float* traj = (s == N_INNER - 1) ? out + (size_t)(iv + 1) * BS * D : nullptr;
            reduce_update<<<512, 256, 0, stream>>>(
                part, b2, z_cur, z_cur, z_h, traj, t, iv);
        }
    }
}

// Round 19
// 7196.474 us; speedup vs baseline: 1.1018x; 1.1018x over previous
//
#include <hip/hip_runtime.h>
#include <hip/hip_bf16.h>
#include <stdint.h>

#define BS 512
#define D 1024
#define H 4096
#define T_STEPS 64
#define N_INNER 4
#define SK 8

typedef __attribute__((ext_vector_type(8))) _Float16 f16x8;
typedef __attribute__((ext_vector_type(4))) float f32x4;
typedef __attribute__((ext_vector_type(4))) unsigned short u16x4;
typedef unsigned short u16;

__device__ __forceinline__ u16 f2h_bits(float f) {
    _Float16 h = (_Float16)f;
    return __builtin_bit_cast(u16, h);
}
__device__ __forceinline__ float h2f(u16 b) {
    return (float)__builtin_bit_cast(_Float16, b);
}
__device__ __forceinline__ float fast_tanh(float x) {
    float e = __expf(2.0f * x);
    return 1.0f - 2.0f / (e + 1.0f);
}

// ---------------- prep kernels ----------------

// src [rows][cols] f32 -> dst [cols][rows] single fp16 (for W1)
__global__ __launch_bounds__(256) void transpose_h(
    const float* __restrict__ src, u16* __restrict__ dst, int rows, int cols) {
    __shared__ float tile[32][33];
    const int tx = threadIdx.x & 31;
    const int ty = threadIdx.x >> 5;
    const int c0 = blockIdx.x * 32, r0 = blockIdx.y * 32;
    #pragma unroll
    for (int i = ty; i < 32; i += 8)
        tile[i][tx] = src[(size_t)(r0 + i) * cols + c0 + tx];
    __syncthreads();
    #pragma unroll
    for (int i = ty; i < 32; i += 8)
        dst[(size_t)(c0 + i) * rows + r0 + tx] = f2h_bits(tile[tx][i]);
}

// src [rows][cols] f32 -> dst_hi/dst_lo [cols][rows] fp16 hi+lo (for W2)
__global__ __launch_bounds__(256) void transpose_split(
    const float* __restrict__ src, u16* __restrict__ dst_hi,
    u16* __restrict__ dst_lo, int rows, int cols) {
    __shared__ float tile[32][33];
    const int tx = threadIdx.x & 31;
    const int ty = threadIdx.x >> 5;
    const int c0 = blockIdx.x * 32, r0 = blockIdx.y * 32;
    #pragma unroll
    for (int i = ty; i < 32; i += 8)
        tile[i][tx] = src[(size_t)(r0 + i) * cols + c0 + tx];
    __syncthreads();
    #pragma unroll
    for (int i = ty; i < 32; i += 8) {
        const float v = tile[tx][i];
        const u16 hi = f2h_bits(v);
        const u16 lo = f2h_bits(v - h2f(hi));
        const size_t idx = (size_t)(c0 + i) * rows + r0 + tx;
        dst_hi[idx] = hi;
        dst_lo[idx] = lo;
    }
}

__global__ __launch_bounds__(256) void init_z(
    const float* __restrict__ z0, float* __restrict__ z_cur,
    u16* __restrict__ z_h, float* __restrict__ out) {
    const int i = blockIdx.x * 256 + threadIdx.x;
    const float v = z0[i];
    z_cur[i] = v;
    z_h[i] = f2h_bits(v);
    out[i] = v;
}

// ---------------- staging helpers (rule #21 swizzle, r4/r10-proven) ----------
// NISS*64 rows x 64 cols fp16 (128 B rows): linear LDS dest, inverse-swizzled src.
template<int NISS>
__device__ __forceinline__ void stage_rows(
    const u16* __restrict__ src, u16* lds, int row0, int ldK, int k0, int tid) {
    #pragma unroll
    for (int i = 0; i < NISS; ++i) {
        const int L = (i * 256 + tid) * 16;        // byte offset in tile
        const int r = L >> 7;
        const int cb = (L & 127) ^ ((r & 7) << 4);
        const size_t goff = (size_t)(row0 + r) * ldK + k0 + (cb >> 1);
        const int ldsoff = (i * 256 + (tid & ~63)) * 8;  // elems, wave-uniform
        __builtin_amdgcn_global_load_lds(
            (const __attribute__((address_space(1))) void*)(src + goff),
            (__attribute__((address_space(3))) void*)(lds + ldsoff), 16, 0, 0);
    }
}

// ---------------- GEMM1 (r17-verbatim): hid = tanh(z @ W1 + b1) --------------
// 64x64 tile, BK=64, 16 K-iters, 4 waves (2x2) of 32x32; depth-3 LDS
// pipeline, counted vmcnt(4). Grid 512 = 2 blocks/CU.
__global__ __launch_bounds__(256, 2) void gemm1_step(
    const u16* __restrict__ A_h, const u16* __restrict__ B_w,
    const float* __restrict__ bias, u16* __restrict__ hid_out) {
    __shared__ __align__(16) u16 lA[3][4096];
    __shared__ __align__(16) u16 lB[3][4096];

    const int tid = threadIdx.x;
    const int bid = blockIdx.x;
    const int xcd = bid & 7, loc = bid >> 3;
    const int tn = xcd * 8 + (loc & 7);   // XCD x writes hid cols [x*512,(x+1)*512)
    const int tm = loc >> 3;
    const int m0 = tm * 64, n0 = tn * 64;

    const int wave = tid >> 6;
    const int lane = tid & 63;
    const int wr = wave >> 1, wc = wave & 1;
    const int l15 = lane & 15;
    const int lgrp = lane >> 4;
    const int lk8 = lgrp * 8;

    f32x4 acc[2][2];
    #pragma unroll
    for (int mi = 0; mi < 2; ++mi)
        #pragma unroll
        for (int ni = 0; ni < 2; ++ni)
            acc[mi][ni] = (f32x4){0.f, 0.f, 0.f, 0.f};

    auto STAGE = [&](int buf, int kt) {
        const int k0 = kt * 64;
        stage_rows<2>(A_h, lA[buf], m0, D, k0, tid);
        stage_rows<2>(B_w, lB[buf], n0, D, k0, tid);  // 4 loads/wave total
    };
    auto COMPUTE = [&](int buf) {
        const char* Ah = (const char*)lA[buf];
        const char* Bh = (const char*)lB[buf];
        #pragma unroll
        for (int kk = 0; kk < 64; kk += 32) {
            f16x8 af[2], bf[2];
            #pragma unroll
            for (int mi = 0; mi < 2; ++mi) {
                const int row = wr * 32 + mi * 16 + l15;
                const int cb = ((kk + lk8) * 2) ^ ((row & 7) << 4);
                af[mi] = *(const f16x8*)(Ah + row * 128 + cb);
            }
            #pragma unroll
            for (int ni = 0; ni < 2; ++ni) {
                const int row = wc * 32 + ni * 16 + l15;
                const int cb = ((kk + lk8) * 2) ^ ((row & 7) << 4);
                bf[ni] = *(const f16x8*)(Bh + row * 128 + cb);
            }
            #pragma unroll
            for (int mi = 0; mi < 2; ++mi)
                #pragma unroll
                for (int ni = 0; ni < 2; ++ni)
                    acc[mi][ni] = __builtin_amdgcn_mfma_f32_16x16x32_f16(
                        af[mi], bf[ni], acc[mi][ni], 0, 0, 0);
        }
    };

    STAGE(0, 0);
    STAGE(1, 1);
    int cur = 0;
    for (int kt = 0; kt < 14; ++kt) {
        asm volatile("s_waitcnt vmcnt(4)" ::: "memory");
        asm volatile("s_barrier" ::: "memory");
        int nb = cur + 2; if (nb >= 3) nb -= 3;
        STAGE(nb, kt + 2);
        COMPUTE(cur);
        ++cur; if (cur == 3) cur = 0;
    }
    asm volatile("s_waitcnt vmcnt(4)" ::: "memory");
    asm volatile("s_barrier" ::: "memory");
    COMPUTE(cur);
    ++cur; if (cur == 3) cur = 0;
    asm volatile("s_waitcnt vmcnt(0)" ::: "memory");
    asm volatile("s_barrier" ::: "memory");
    COMPUTE(cur);

    const int crow_base = m0 + wr * 32;
    const int ccol_base = n0 + wc * 32;
    #pragma unroll
    for (int mi = 0; mi < 2; ++mi)
        #pragma unroll
        for (int ni = 0; ni < 2; ++ni) {
            const int col = ccol_base + ni * 16 + l15;
            const float b = bias[col];
            #pragma unroll
            for (int r = 0; r < 4; ++r) {
                const int row = crow_base + mi * 16 + lgrp * 4 + r;
                const float v = fast_tanh(acc[mi][ni][r] + b);
                hid_out[(size_t)row * H + col] = f2h_bits(v);
            }
        }
}

// ---------------- GEMM2: 128x64, SK=8, W2 split hi/lo ------------------------
// r17 structure; ONLY change: XCD map is sk-aligned (sk = bid&7) so each
// XCD's blocks read the hid column-slice [sk*512,(sk+1)*512) that gemm1
// blocks on the SAME XCD wrote -> A-staging hits local L2, not LLC.
__global__ __launch_bounds__(256, 2) void gemm2_step(
    const u16* __restrict__ A_h,
    const u16* __restrict__ B_hi, const u16* __restrict__ B_lo,
    float* __restrict__ part) {
    __shared__ __align__(16) u16 lA[2][8192];     // 128x64
    __shared__ __align__(16) u16 lBh[2][4096];    // 64x64
    __shared__ __align__(16) u16 lBl[2][4096];

    const int tid = threadIdx.x;
    const int bid = blockIdx.x;
    const int sk = bid & 7;                       // XCD owns its K-slice
    const int loc = bid >> 3;                     // 0..63
    const int tn = loc & 15;                      // 0..15
    const int tm = loc >> 4;                      // 0..3
    const int m0 = tm * 128, n0 = tn * 64;
    const int k0b = sk * 512;

    const int wave = tid >> 6;
    const int lane = tid & 63;
    const int wr = wave >> 1, wc = wave & 1;      // wave owns 64x32
    const int l15 = lane & 15;
    const int lgrp = lane >> 4;
    const int lk8 = lgrp * 8;

    f32x4 acc[4][2];
    #pragma unroll
    for (int mi = 0; mi < 4; ++mi)
        #pragma unroll
        for (int ni = 0; ni < 2; ++ni)
            acc[mi][ni] = (f32x4){0.f, 0.f, 0.f, 0.f};

    auto STAGE = [&](int buf, int kt) {
        const int k0 = k0b + kt * 64;
        stage_rows<4>(A_h,  lA[buf],  m0, H, k0, tid);
        stage_rows<2>(B_hi, lBh[buf], n0, H, k0, tid);
        stage_rows<2>(B_lo, lBl[buf], n0, H, k0, tid);   // 8 loads/wave
    };
    auto COMPUTE = [&](int buf) {
        const char* Ah = (const char*)lA[buf];
        const char* Bh = (const char*)lBh[buf];
        const char* Bl = (const char*)lBl[buf];
        #pragma unroll
        for (int kk = 0; kk < 64; kk += 32) {
            f16x8 af[4], bfh[2], bfl[2];
            #pragma unroll
            for (int mi = 0; mi < 4; ++mi) {
                const int row = wr * 64 + mi * 16 + l15;
                const int cb = ((kk + lk8) * 2) ^ ((row & 7) << 4);
                af[mi] = *(const f16x8*)(Ah + row * 128 + cb);
            }
            #pragma unroll
            for (int ni = 0; ni < 2; ++ni) {
                const int row = wc * 32 + ni * 16 + l15;
                const int cb = ((kk + lk8) * 2) ^ ((row & 7) << 4);
                bfh[ni] = *(const f16x8*)(Bh + row * 128 + cb);
                bfl[ni] = *(const f16x8*)(Bl + row * 128 + cb);
            }
            #pragma unroll
            for (int mi = 0; mi < 4; ++mi)
                #pragma unroll
                for (int ni = 0; ni < 2; ++ni) {
                    acc[mi][ni] = __builtin_amdgcn_mfma_f32_16x16x32_f16(
                        af[mi], bfh[ni], acc[mi][ni], 0, 0, 0);
                    acc[mi][ni] = __builtin_amdgcn_mfma_f32_16x16x32_f16(
                        af[mi], bfl[ni], acc[mi][ni], 0, 0, 0);
                }
        }
    };

    STAGE(0, 0);
    STAGE(1, 1);
    int cur = 0;
    for (int kt = 0; kt < 8; ++kt) {
        if (kt < 7) asm volatile("s_waitcnt vmcnt(8)" ::: "memory");
        else        asm volatile("s_waitcnt vmcnt(0)" ::: "memory");
        asm volatile("s_barrier" ::: "memory");
        COMPUTE(cur);
        if (kt < 6) {
            asm volatile("s_barrier" ::: "memory");
            STAGE(cur, kt + 2);
        }
        cur ^= 1;
    }

    float* p = part + (size_t)sk * BS * D;
    const int crow_base = m0 + wr * 64;
    const int ccol_base = n0 + wc * 32;
    #pragma unroll
    for (int mi = 0; mi < 4; ++mi)
        #pragma unroll
        for (int ni = 0; ni < 2; ++ni) {
            const int col = ccol_base + ni * 16 + l15;
            #pragma unroll
            for (int r = 0; r < 4; ++r) {
                const int row = crow_base + mi * 16 + lgrp * 4 + r;
                p[(size_t)row * D + col] = acc[mi][ni][r];
            }
        }
}

// ---------------- split-K reduce (SK=8) + Euler update (r17-verbatim) --------
__global__ __launch_bounds__(256) void reduce_update(
    const float* __restrict__ part, const float* __restrict__ b2,
    const float* __restrict__ z_in, float* __restrict__ z_out,
    u16* __restrict__ zh,
    float* __restrict__ traj, const float* __restrict__ tptr, int iv) {
    const int i = (blockIdx.x * 256 + threadIdx.x) * 4;
    const size_t SZ = (size_t)BS * D;
    float4 s = *(const float4*)(part + i);
    #pragma unroll
    for (int k = 1; k < SK; ++k) {
        const float4 pk = *(const float4*)(part + (size_t)k * SZ + i);
        s.x += pk.x; s.y += pk.y; s.z += pk.z; s.w += pk.w;
    }
    const float4 b = *(const float4*)(b2 + (i & (D - 1)));
    const float4 z = *(const float4*)(z_in + i);
    const float h = fabsf(tptr[iv + 1] - tptr[iv]) * (1.0f / N_INNER);
    float4 v;
    v.x = z.x + h * (s.x + b.x);
    v.y = z.y + h * (s.y + b.y);
    v.z = z.z + h * (s.z + b.z);
    v.w = z.w + h * (s.w + b.w);
    *(float4*)(z_out + i) = v;
    u16x4 h4;
    h4.x = f2h_bits(v.x);
    h4.y = f2h_bits(v.y);
    h4.z = f2h_bits(v.z);
    h4.w = f2h_bits(v.w);
    *(u16x4*)(zh + i) = h4;
    if (traj) *(float4*)(traj + i) = v;
}

// ---------------- host ----------------

extern "C" void kernel_launch(void* const* d_in, const int* in_sizes, int n_in,
                              void* d_out, int out_size, void* d_ws, size_t ws_size,
                              hipStream_t stream) {
    const float* z0 = (const float*)d_in[0];
    const float* t  = (const float*)d_in[1];
    const float* W1 = (const float*)d_in[2];
    const float* b1 = (const float*)d_in[3];
    const float* W2 = (const float*)d_in[4];
    const float* b2 = (const float*)d_in[5];
    float* out = (float*)d_out;

    char* ws = (char*)d_ws;
    u16*   W1T    = (u16*)(ws);                        // [H][D] fp16, 8 MB
    u16*   W2T_hi = (u16*)(ws + (8u << 20));           // [D][H] fp16, 8 MB
    u16*   W2T_lo = (u16*)(ws + (16u << 20));
    float* z_cur  = (float*)(ws + (24u << 20));        // [BS][D] f32, 2 MB
    u16*   z_h    = (u16*)(ws + (26u << 20));          // [BS][D] fp16, 1 MB
    u16*   hid_h  = (u16*)(ws + (28u << 20));          // [BS][H] fp16, 4 MB
    float* part   = (float*)(ws + (32u << 20));        // SK x [BS][D] f32, 16 MB

    transpose_h<<<dim3(H / 32, D / 32), 256, 0, stream>>>(W1, W1T, D, H);
    transpose_split<<<dim3(D / 32, H / 32), 256, 0, stream>>>(W2, W2T_hi, W2T_lo, H, D);
    init_z<<<(BS * D) / 256, 256, 0, stream>>>(z0, z_cur, z_h, out);

    for (int iv = 0; iv < T_STEPS - 1; ++iv) {
        for (int s = 0; s < N_INNER; ++s) {
            gemm1_step<<<512, 256, 0, stream>>>(z_h, W1T, b1, hid_h);
            gemm2_step<<<512, 256, 0, stream>>>(hid_h, W2T_hi, W2T_lo, part);
            float* traj = (s == N_INNER - 1) ? out + (size_t)(iv + 1) * BS * D : nullptr;
            reduce_update<<<512, 256, 0, stream>>>(
                part, b2, z_cur, z_cur, z_h, traj, t, iv);
        }
    }
}

// Round 20
// 6579.889 us; speedup vs baseline: 1.2051x; 1.0937x over previous
//
#include <hip/hip_runtime.h>
#include <hip/hip_bf16.h>
#include <stdint.h>

#define BS 512
#define D 1024
#define H 4096
#define T_STEPS 64
#define N_INNER 4
#define SK 8

typedef __attribute__((ext_vector_type(8))) _Float16 f16x8;
typedef __attribute__((ext_vector_type(4))) float f32x4;
typedef __attribute__((ext_vector_type(4))) unsigned short u16x4;
typedef unsigned short u16;

__device__ __forceinline__ u16 f2h_bits(float f) {
    _Float16 h = (_Float16)f;
    return __builtin_bit_cast(u16, h);
}
__device__ __forceinline__ float h2f(u16 b) {
    return (float)__builtin_bit_cast(_Float16, b);
}
__device__ __forceinline__ float fast_tanh(float x) {
    float e = __expf(2.0f * x);
    return 1.0f - 2.0f / (e + 1.0f);
}

// ---------------- prep kernels ----------------

// src [rows][cols] f32 -> dst [cols][rows] single fp16 (for W1)
__global__ __launch_bounds__(256) void transpose_h(
    const float* __restrict__ src, u16* __restrict__ dst, int rows, int cols) {
    __shared__ float tile[32][33];
    const int tx = threadIdx.x & 31;
    const int ty = threadIdx.x >> 5;
    const int c0 = blockIdx.x * 32, r0 = blockIdx.y * 32;
    #pragma unroll
    for (int i = ty; i < 32; i += 8)
        tile[i][tx] = src[(size_t)(r0 + i) * cols + c0 + tx];
    __syncthreads();
    #pragma unroll
    for (int i = ty; i < 32; i += 8)
        dst[(size_t)(c0 + i) * rows + r0 + tx] = f2h_bits(tile[tx][i]);
}

// src [rows][cols] f32 -> dst_hi/dst_lo [cols][rows] fp16 hi+lo (for W2)
__global__ __launch_bounds__(256) void transpose_split(
    const float* __restrict__ src, u16* __restrict__ dst_hi,
    u16* __restrict__ dst_lo, int rows, int cols) {
    __shared__ float tile[32][33];
    const int tx = threadIdx.x & 31;
    const int ty = threadIdx.x >> 5;
    const int c0 = blockIdx.x * 32, r0 = blockIdx.y * 32;
    #pragma unroll
    for (int i = ty; i < 32; i += 8)
        tile[i][tx] = src[(size_t)(r0 + i) * cols + c0 + tx];
    __syncthreads();
    #pragma unroll
    for (int i = ty; i < 32; i += 8) {
        const float v = tile[tx][i];
        const u16 hi = f2h_bits(v);
        const u16 lo = f2h_bits(v - h2f(hi));
        const size_t idx = (size_t)(c0 + i) * rows + r0 + tx;
        dst_hi[idx] = hi;
        dst_lo[idx] = lo;
    }
}

__global__ __launch_bounds__(256) void init_z(
    const float* __restrict__ z0, float* __restrict__ z_cur,
    u16* __restrict__ z_h, float* __restrict__ out) {
    const int i = blockIdx.x * 256 + threadIdx.x;
    const float v = z0[i];
    z_cur[i] = v;
    z_h[i] = f2h_bits(v);
    out[i] = v;
}

// ---------------- staging helpers (rule #21 swizzle) -------------------------
// NISS*64 rows x 64 cols fp16 (128 B rows): linear LDS dest, swizzled src.
template<int NISS>
__device__ __forceinline__ void stage_rows(
    const u16* __restrict__ src, u16* lds, int row0, int ldK, int k0, int tid) {
    #pragma unroll
    for (int i = 0; i < NISS; ++i) {
        const int L = (i * 256 + tid) * 16;        // byte offset in tile
        const int r = L >> 7;
        const int cb = (L & 127) ^ ((r & 7) << 4);
        const size_t goff = (size_t)(row0 + r) * ldK + k0 + (cb >> 1);
        const int ldsoff = (i * 256 + (tid & ~63)) * 8;  // elems, wave-uniform
        __builtin_amdgcn_global_load_lds(
            (const __attribute__((address_space(1))) void*)(src + goff),
            (__attribute__((address_space(3))) void*)(lds + ldsoff), 16, 0, 0);
    }
}

// NISS*16 rows x 128 cols fp16 (256 B rows) — r6/r7-proven 256B-row swizzle.
template<int NISS>
__device__ __forceinline__ void stage_rows256(
    const u16* __restrict__ src, u16* lds, int row0, int ldK, int k0, int tid) {
    #pragma unroll
    for (int i = 0; i < NISS; ++i) {
        const int L = (i * 256 + tid) * 16;        // byte offset in tile
        const int r = L >> 8;                      // 256 B rows
        const int cb = (L & 255) ^ ((r & 7) << 4);
        const size_t goff = (size_t)(row0 + r) * ldK + k0 + (cb >> 1);
        const int ldsoff = (i * 256 + (tid & ~63)) * 8;
        __builtin_amdgcn_global_load_lds(
            (const __attribute__((address_space(1))) void*)(src + goff),
            (__attribute__((address_space(3))) void*)(lds + ldsoff), 16, 0, 0);
    }
}

// ---------------- GEMM1: 64x64 tile, BK=128, single-fp16 W1 ------------------
// hid = tanh(z @ W1 + b1). 8 kt of BK=128; 4 waves (2x2) of 32x32 (acc 2x2).
// Depth-2 double-buffer (64 KB LDS -> 2 blocks/CU), counted vmcnt(8)
// (A 4 + B 4 loads/wave/stage), 2 barriers/iter — loop structure cloned
// from r17's proven gemm2. K consumed in identical 32-chunk order as r19
// -> output bit-exact.
__global__ __launch_bounds__(256, 2) void gemm1_step(
    const u16* __restrict__ A_h, const u16* __restrict__ B_w,
    const float* __restrict__ bias, u16* __restrict__ hid_out) {
    __shared__ __align__(16) u16 lA[2][8192];     // 64 x 128
    __shared__ __align__(16) u16 lB[2][8192];     // 64 x 128

    const int tid = threadIdx.x;
    const int bid = blockIdx.x;
    const int xcd = bid & 7, loc = bid >> 3;
    const int tn = xcd * 8 + (loc & 7);   // XCD x writes hid cols [x*512,(x+1)*512)
    const int tm = loc >> 3;
    const int m0 = tm * 64, n0 = tn * 64;

    const int wave = tid >> 6;
    const int lane = tid & 63;
    const int wr = wave >> 1, wc = wave & 1;
    const int l15 = lane & 15;
    const int lgrp = lane >> 4;
    const int lk8 = lgrp * 8;

    f32x4 acc[2][2];
    #pragma unroll
    for (int mi = 0; mi < 2; ++mi)
        #pragma unroll
        for (int ni = 0; ni < 2; ++ni)
            acc[mi][ni] = (f32x4){0.f, 0.f, 0.f, 0.f};

    auto STAGE = [&](int buf, int kt) {
        const int k0 = kt * 128;
        stage_rows256<4>(A_h, lA[buf], m0, D, k0, tid);
        stage_rows256<4>(B_w, lB[buf], n0, D, k0, tid);   // 8 loads/wave
    };
    auto COMPUTE = [&](int buf) {
        const char* Ah = (const char*)lA[buf];
        const char* Bh = (const char*)lB[buf];
        #pragma unroll
        for (int kk = 0; kk < 128; kk += 32) {
            f16x8 af[2], bf[2];
            #pragma unroll
            for (int mi = 0; mi < 2; ++mi) {
                const int row = wr * 32 + mi * 16 + l15;
                const int cb = ((kk + lk8) * 2) ^ ((row & 7) << 4);
                af[mi] = *(const f16x8*)(Ah + row * 256 + cb);
            }
            #pragma unroll
            for (int ni = 0; ni < 2; ++ni) {
                const int row = wc * 32 + ni * 16 + l15;
                const int cb = ((kk + lk8) * 2) ^ ((row & 7) << 4);
                bf[ni] = *(const f16x8*)(Bh + row * 256 + cb);
            }
            #pragma unroll
            for (int mi = 0; mi < 2; ++mi)
                #pragma unroll
                for (int ni = 0; ni < 2; ++ni)
                    acc[mi][ni] = __builtin_amdgcn_mfma_f32_16x16x32_f16(
                        af[mi], bf[ni], acc[mi][ni], 0, 0, 0);
        }
    };

    STAGE(0, 0);
    STAGE(1, 1);
    int cur = 0;
    for (int kt = 0; kt < 8; ++kt) {
        if (kt < 7) asm volatile("s_waitcnt vmcnt(8)" ::: "memory");
        else        asm volatile("s_waitcnt vmcnt(0)" ::: "memory");
        asm volatile("s_barrier" ::: "memory");
        COMPUTE(cur);
        if (kt < 6) {
            asm volatile("s_barrier" ::: "memory");   // all waves done with cur
            STAGE(cur, kt + 2);
        }
        cur ^= 1;
    }

    const int crow_base = m0 + wr * 32;
    const int ccol_base = n0 + wc * 32;
    #pragma unroll
    for (int mi = 0; mi < 2; ++mi)
        #pragma unroll
        for (int ni = 0; ni < 2; ++ni) {
            const int col = ccol_base + ni * 16 + l15;
            const float b = bias[col];
            #pragma unroll
            for (int r = 0; r < 4; ++r) {
                const int row = crow_base + mi * 16 + lgrp * 4 + r;
                const float v = fast_tanh(acc[mi][ni][r] + b);
                hid_out[(size_t)row * H + col] = f2h_bits(v);
            }
        }
}

// ---------------- GEMM2 (r19-verbatim): 128x64, SK=8 sk-aligned XCD map ------
__global__ __launch_bounds__(256, 2) void gemm2_step(
    const u16* __restrict__ A_h,
    const u16* __restrict__ B_hi, const u16* __restrict__ B_lo,
    float* __restrict__ part) {
    __shared__ __align__(16) u16 lA[2][8192];     // 128x64
    __shared__ __align__(16) u16 lBh[2][4096];    // 64x64
    __shared__ __align__(16) u16 lBl[2][4096];

    const int tid = threadIdx.x;
    const int bid = blockIdx.x;
    const int sk = bid & 7;                       // XCD owns its K-slice
    const int loc = bid >> 3;                     // 0..63
    const int tn = loc & 15;                      // 0..15
    const int tm = loc >> 4;                      // 0..3
    const int m0 = tm * 128, n0 = tn * 64;
    const int k0b = sk * 512;

    const int wave = tid >> 6;
    const int lane = tid & 63;
    const int wr = wave >> 1, wc = wave & 1;      // wave owns 64x32
    const int l15 = lane & 15;
    const int lgrp = lane >> 4;
    const int lk8 = lgrp * 8;

    f32x4 acc[4][2];
    #pragma unroll
    for (int mi = 0; mi < 4; ++mi)
        #pragma unroll
        for (int ni = 0; ni < 2; ++ni)
            acc[mi][ni] = (f32x4){0.f, 0.f, 0.f, 0.f};

    auto STAGE = [&](int buf, int kt) {
        const int k0 = k0b + kt * 64;
        stage_rows<4>(A_h,  lA[buf],  m0, H, k0, tid);
        stage_rows<2>(B_hi, lBh[buf], n0, H, k0, tid);
        stage_rows<2>(B_lo, lBl[buf], n0, H, k0, tid);   // 8 loads/wave
    };
    auto COMPUTE = [&](int buf) {
        const char* Ah = (const char*)lA[buf];
        const char* Bh = (const char*)lBh[buf];
        const char* Bl = (const char*)lBl[buf];
        #pragma unroll
        for (int kk = 0; kk < 64; kk += 32) {
            f16x8 af[4], bfh[2], bfl[2];
            #pragma unroll
            for (int mi = 0; mi < 4; ++mi) {
                const int row = wr * 64 + mi * 16 + l15;
                const int cb = ((kk + lk8) * 2) ^ ((row & 7) << 4);
                af[mi] = *(const f16x8*)(Ah + row * 128 + cb);
            }
            #pragma unroll
            for (int ni = 0; ni < 2; ++ni) {
                const int row = wc * 32 + ni * 16 + l15;
                const int cb = ((kk + lk8) * 2) ^ ((row & 7) << 4);
                bfh[ni] = *(const f16x8*)(Bh + row * 128 + cb);
                bfl[ni] = *(const f16x8*)(Bl + row * 128 + cb);
            }
            #pragma unroll
            for (int mi = 0; mi < 4; ++mi)
                #pragma unroll
                for (int ni = 0; ni < 2; ++ni) {
                    acc[mi][ni] = __builtin_amdgcn_mfma_f32_16x16x32_f16(
                        af[mi], bfh[ni], acc[mi][ni], 0, 0, 0);
                    acc[mi][ni] = __builtin_amdgcn_mfma_f32_16x16x32_f16(
                        af[mi], bfl[ni], acc[mi][ni], 0, 0, 0);
                }
        }
    };

    STAGE(0, 0);
    STAGE(1, 1);
    int cur = 0;
    for (int kt = 0; kt < 8; ++kt) {
        if (kt < 7) asm volatile("s_waitcnt vmcnt(8)" ::: "memory");
        else        asm volatile("s_waitcnt vmcnt(0)" ::: "memory");
        asm volatile("s_barrier" ::: "memory");
        COMPUTE(cur);
        if (kt < 6) {
            asm volatile("s_barrier" ::: "memory");
            STAGE(cur, kt + 2);
        }
        cur ^= 1;
    }

    float* p = part + (size_t)sk * BS * D;
    const int crow_base = m0 + wr * 64;
    const int ccol_base = n0 + wc * 32;
    #pragma unroll
    for (int mi = 0; mi < 4; ++mi)
        #pragma unroll
        for (int ni = 0; ni < 2; ++ni) {
            const int col = ccol_base + ni * 16 + l15;
            #pragma unroll
            for (int r = 0; r < 4; ++r) {
                const int row = crow_base + mi * 16 + lgrp * 4 + r;
                p[(size_t)row * D + col] = acc[mi][ni][r];
            }
        }
}

// ---------------- split-K reduce (SK=8) + Euler update (r19-verbatim) --------
__global__ __launch_bounds__(256) void reduce_update(
    const float* __restrict__ part, const float* __restrict__ b2,
    const float* __restrict__ z_in, float* __restrict__ z_out,
    u16* __restrict__ zh,
    float* __restrict__ traj, const float* __restrict__ tptr, int iv) {
    const int i = (blockIdx.x * 256 + threadIdx.x) * 4;
    const size_t SZ = (size_t)BS * D;
    float4 s = *(const float4*)(part + i);
    #pragma unroll
    for (int k = 1; k < SK; ++k) {
        const float4 pk = *(const float4*)(part + (size_t)k * SZ + i);
        s.x += pk.x; s.y += pk.y; s.z += pk.z; s.w += pk.w;
    }
    const float4 b = *(const float4*)(b2 + (i & (D - 1)));
    const float4 z = *(const float4*)(z_in + i);
    const float h = fabsf(tptr[iv + 1] - tptr[iv]) * (1.0f / N_INNER);
    float4 v;
    v.x = z.x + h * (s.x + b.x);
    v.y = z.y + h * (s.y + b.y);
    v.z = z.z + h * (s.z + b.z);
    v.w = z.w + h * (s.w + b.w);
    *(float4*)(z_out + i) = v;
    u16x4 h4;
    h4.x = f2h_bits(v.x);
    h4.y = f2h_bits(v.y);
    h4.z = f2h_bits(v.z);
    h4.w = f2h_bits(v.w);
    *(u16x4*)(zh + i) = h4;
    if (traj) *(float4*)(traj + i) = v;
}

// ---------------- host ----------------

extern "C" void kernel_launch(void* const* d_in, const int* in_sizes, int n_in,
                              void* d_out, int out_size, void* d_ws, size_t ws_size,
                              hipStream_t stream) {
    const float* z0 = (const float*)d_in[0];
    const float* t  = (const float*)d_in[1];
    const float* W1 = (const float*)d_in[2];
    const float* b1 = (const float*)d_in[3];
    const float* W2 = (const float*)d_in[4];
    const float* b2 = (const float*)d_in[5];
    float* out = (float*)d_out;

    char* ws = (char*)d_ws;
    u16*   W1T    = (u16*)(ws);                        // [H][D] fp16, 8 MB
    u16*   W2T_hi = (u16*)(ws + (8u << 20));           // [D][H] fp16, 8 MB
    u16*   W2T_lo = (u16*)(ws + (16u << 20));
    float* z_cur  = (float*)(ws + (24u << 20));        // [BS][D] f32, 2 MB
    u16*   z_h    = (u16*)(ws + (26u << 20));          // [BS][D] fp16, 1 MB
    u16*   hid_h  = (u16*)(ws + (28u << 20));          // [BS][H] fp16, 4 MB
    float* part   = (float*)(ws + (32u << 20));        // SK x [BS][D] f32, 16 MB

    transpose_h<<<dim3(H / 32, D / 32), 256, 0, stream>>>(W1, W1T, D, H);
    transpose_split<<<dim3(D / 32, H / 32), 256, 0, stream>>>(W2, W2T_hi, W2T_lo, H, D);
    init_z<<<(BS * D) / 256, 256, 0, stream>>>(z0, z_cur, z_h, out);

    for (int iv = 0; iv < T_STEPS - 1; ++iv) {
        for (int s = 0; s < N_INNER; ++s) {
            gemm1_step<<<512, 256, 0, stream>>>(z_h, W1T, b1, hid_h);
            gemm2_step<<<512, 256, 0, stream>>>(hid_h, W2T_hi, W2T_lo, part);
            float* traj = (s == N_INNER - 1) ? out + (size_t)(iv + 1) * BS * D : nullptr;
            reduce_update<<<512, 256, 0, stream>>>(
                part, b2, z_cur, z_cur, z_h, traj, t, iv);
        }
    }
}